// Round 1
// baseline (900.970 us; speedup 1.0000x reference)
//
#include <hip/hip_runtime.h>
#include <hip/hip_bf16.h>

// ---------------- problem constants ----------------
#define N_VEC   16384      // 16*32*32 latent vectors
#define K_CODES 8192
#define D_DIM   256
#define KSPLIT  4

// d_out layout (float32 elements)
#define ZQ_SIZE  (16*256*32*32)          // 4194304
#define DIFF_OFF ZQ_SIZE                 // 4194304
#define IDX_OFF  (ZQ_SIZE + 1)           // 4194305
#define PERP_OFF (ZQ_SIZE + 1 + N_VEC)   // 4210689

// ws layout (bytes); total ~610 KB
#define WS_ENORM 0
#define WS_PBEST (K_CODES * 4)                       // 32768
#define WS_PK    (WS_PBEST + KSPLIT * N_VEC * 4)     // +262144
#define WS_IDX   (WS_PK + KSPLIT * N_VEC * 4)        // +262144
#define WS_PART  (WS_IDX + N_VEC * 4)                // +65536

// GEMM tiling
#define BM   128
#define BN   128
#define BKD  32
#define LDSA 132   // padded LDS stride (floats); 132*4=528 B, 16B-aligned rows

// ---------------- kernel 1: codebook norms ----------------
__global__ __launch_bounds__(256) void enorm_kernel(const float* __restrict__ E,
                                                    float* __restrict__ enorm) {
    const int tid  = threadIdx.x;
    const int lane = tid & 63;
    const int wid  = tid >> 6;
    const int code = blockIdx.x * 4 + wid;
    const float4 v = *reinterpret_cast<const float4*>(E + (size_t)code * D_DIM + lane * 4);
    float s = v.x * v.x + v.y * v.y + v.z * v.z + v.w * v.w;
    #pragma unroll
    for (int off = 32; off; off >>= 1) s += __shfl_down(s, off);
    if (lane == 0) enorm[code] = s;
}

// ---------------- kernel 2: fused distance GEMM + argmin ----------------
__global__ __launch_bounds__(256, 2) void vq_argmin_kernel(
        const float* __restrict__ Z, const float* __restrict__ E,
        const float* __restrict__ enorm,
        float* __restrict__ part_best, int* __restrict__ part_k) {
    __shared__ float As[BKD * LDSA];
    __shared__ float Bs[BKD * LDSA];

    const int tid  = threadIdx.x;
    const int tx   = tid & 15;    // col group
    const int ty   = tid >> 4;    // row group
    const int row0 = blockIdx.x * BM;
    const int ksp  = blockIdx.y;
    const int kbase0 = ksp * (K_CODES / KSPLIT);

    const int sseg = tid & 7;     // staging: d-segment (float4)
    const int srow = tid >> 3;    // staging: row 0..31

    float best[8];
    int   bestk[8];
    #pragma unroll
    for (int i = 0; i < 8; ++i) { best[i] = 3.0e38f; bestk[i] = 0; }

    for (int kb = 0; kb < (K_CODES / KSPLIT) / BN; ++kb) {
        const int kofs = kbase0 + kb * BN;
        const float4 en0 = *reinterpret_cast<const float4*>(enorm + kofs + 4 * tx);
        const float4 en1 = *reinterpret_cast<const float4*>(enorm + kofs + 64 + 4 * tx);

        float acc[8][8];
        #pragma unroll
        for (int i = 0; i < 8; ++i)
            #pragma unroll
            for (int j = 0; j < 8; ++j) acc[i][j] = 0.0f;

        for (int dt = 0; dt < D_DIM / BKD; ++dt) {
            __syncthreads();
            // stage A (z rows) and B (codes), transposed to d-major
            #pragma unroll
            for (int p = 0; p < 4; ++p) {
                const int r = p * 32 + srow;
                const float4 va = *reinterpret_cast<const float4*>(
                    Z + (size_t)(row0 + r) * D_DIM + dt * BKD + sseg * 4);
                As[(sseg * 4 + 0) * LDSA + r] = va.x;
                As[(sseg * 4 + 1) * LDSA + r] = va.y;
                As[(sseg * 4 + 2) * LDSA + r] = va.z;
                As[(sseg * 4 + 3) * LDSA + r] = va.w;
                const float4 vb = *reinterpret_cast<const float4*>(
                    E + (size_t)(kofs + r) * D_DIM + dt * BKD + sseg * 4);
                Bs[(sseg * 4 + 0) * LDSA + r] = vb.x;
                Bs[(sseg * 4 + 1) * LDSA + r] = vb.y;
                Bs[(sseg * 4 + 2) * LDSA + r] = vb.z;
                Bs[(sseg * 4 + 3) * LDSA + r] = vb.w;
            }
            __syncthreads();

            #pragma unroll 8
            for (int d = 0; d < BKD; ++d) {
                const float4 a0 = *reinterpret_cast<const float4*>(&As[d * LDSA + 8 * ty]);
                const float4 a1 = *reinterpret_cast<const float4*>(&As[d * LDSA + 8 * ty + 4]);
                const float4 b0 = *reinterpret_cast<const float4*>(&Bs[d * LDSA + 4 * tx]);
                const float4 b1 = *reinterpret_cast<const float4*>(&Bs[d * LDSA + 64 + 4 * tx]);
                const float aa[8] = {a0.x, a0.y, a0.z, a0.w, a1.x, a1.y, a1.z, a1.w};
                const float bb[8] = {b0.x, b0.y, b0.z, b0.w, b1.x, b1.y, b1.z, b1.w};
                #pragma unroll
                for (int i = 0; i < 8; ++i)
                    #pragma unroll
                    for (int j = 0; j < 8; ++j) acc[i][j] += aa[i] * bb[j];
            }
        }

        // epilogue: score = ||e||^2 - 2 z.e ; running argmin (k-ascending scan)
        const float en[8] = {en0.x, en0.y, en0.z, en0.w, en1.x, en1.y, en1.z, en1.w};
        const int c0 = kofs + 4 * tx;
        const int c1 = kofs + 64 + 4 * tx;
        #pragma unroll
        for (int i = 0; i < 8; ++i) {
            #pragma unroll
            for (int j = 0; j < 4; ++j) {
                const float s = en[j] - 2.0f * acc[i][j];
                if (s < best[i]) { best[i] = s; bestk[i] = c0 + j; }
            }
            #pragma unroll
            for (int j = 4; j < 8; ++j) {
                const float s = en[j] - 2.0f * acc[i][j];
                if (s < best[i]) { best[i] = s; bestk[i] = c1 + (j - 4); }
            }
        }
    }

    // reduce across the 16 tx-lanes sharing each row (lexicographic: min score, then min k)
    #pragma unroll
    for (int i = 0; i < 8; ++i) {
        float v = best[i];
        int   k = bestk[i];
        #pragma unroll
        for (int off = 1; off < 16; off <<= 1) {
            const float ov = __shfl_xor(v, off);
            const int   ok = __shfl_xor(k, off);
            if (ov < v || (ov == v && ok < k)) { v = ov; k = ok; }
        }
        if (tx == 0) {
            const int row = row0 + ty * 8 + i;
            part_best[ksp * N_VEC + row] = v;
            part_k[ksp * N_VEC + row]    = k;
        }
    }
}

// ---------------- kernel 3: merge K-splits ----------------
__global__ __launch_bounds__(256) void merge_kernel(const float* __restrict__ pb,
                                                    const int* __restrict__ pk,
                                                    int* __restrict__ idx_i,
                                                    float* __restrict__ out_idx) {
    const int n = blockIdx.x * 256 + threadIdx.x;
    float bv = pb[n];
    int   bk = pk[n];
    #pragma unroll
    for (int s = 1; s < KSPLIT; ++s) {
        const float v = pb[s * N_VEC + n];
        const int   k = pk[s * N_VEC + n];
        if (v < bv) { bv = v; bk = k; }   // splits scanned k-ascending -> strict < keeps first min
    }
    idx_i[n]   = bk;
    out_idx[n] = (float)bk;
}

// ---------------- kernel 4: gather + NCHW transpose + commitment-loss partial ----------------
__global__ __launch_bounds__(256) void gather_kernel(const float* __restrict__ Z,
                                                     const float* __restrict__ E,
                                                     const int* __restrict__ idx_i,
                                                     float* __restrict__ out,
                                                     float* __restrict__ partials) {
    __shared__ float Ls[128 * 65];
    __shared__ int   sIdx[64];
    __shared__ float red[4];

    const int tid = threadIdx.x;
    const int g   = blockIdx.x;       // 0..255, 64 latent vectors each
    const int n0  = g * 64;
    const int b   = n0 >> 10;
    const int hwbase = n0 & 1023;

    if (tid < 64) sIdx[tid] = idx_i[n0 + tid];
    __syncthreads();

    // commitment loss partial: coalesced Z read, gathered E read (L2/L3 resident)
    float sq = 0.0f;
    {
        const int c4   = tid & 63;
        const int rsub = tid >> 6;
        #pragma unroll
        for (int p = 0; p < 16; ++p) {
            const int r = p * 4 + rsub;
            const float4 z4 = *reinterpret_cast<const float4*>(Z + (size_t)(n0 + r) * D_DIM + c4 * 4);
            const float4 e4 = *reinterpret_cast<const float4*>(E + (size_t)sIdx[r] * D_DIM + c4 * 4);
            const float dx = e4.x - z4.x, dy = e4.y - z4.y, dz = e4.z - z4.z, dw = e4.w - z4.w;
            sq += dx * dx + dy * dy + dz * dz + dw * dw;
        }
    }
    #pragma unroll
    for (int off = 32; off; off >>= 1) sq += __shfl_down(sq, off);
    if ((tid & 63) == 0) red[tid >> 6] = sq;
    __syncthreads();
    if (tid == 0) partials[g] = red[0] + red[1] + red[2] + red[3];

    // z_q gather + transpose (b,hw,c) -> (b,c,hw), two c-halves via padded LDS tile
    for (int h = 0; h < 2; ++h) {
        __syncthreads();
        const int rowl = tid >> 2;   // 0..63
        const int qs   = tid & 3;
        const float* erow = E + (size_t)sIdx[rowl] * D_DIM + h * 128;
        #pragma unroll
        for (int m = 0; m < 8; ++m) {
            const int c4 = m * 4 + qs;
            const float4 v = *reinterpret_cast<const float4*>(erow + c4 * 4);
            Ls[(c4 * 4 + 0) * 65 + rowl] = v.x;
            Ls[(c4 * 4 + 1) * 65 + rowl] = v.y;
            Ls[(c4 * 4 + 2) * 65 + rowl] = v.z;
            Ls[(c4 * 4 + 3) * 65 + rowl] = v.w;
        }
        __syncthreads();
        const int wl   = tid & 63;
        const int csub = tid >> 6;   // 0..3
        #pragma unroll
        for (int pc = 0; pc < 32; ++pc) {
            const int c_l = pc * 4 + csub;            // 0..127
            const int c   = h * 128 + c_l;
            out[((size_t)(b * 256 + c)) * 1024 + hwbase + wl] = Ls[c_l * 65 + wl];
        }
    }
}

// ---------------- kernel 5: finalize scalars ----------------
__global__ __launch_bounds__(256) void final_kernel(const float* __restrict__ partials,
                                                    float* __restrict__ out) {
    __shared__ float red[4];
    const int tid = threadIdx.x;
    float s = partials[tid];
    #pragma unroll
    for (int off = 32; off; off >>= 1) s += __shfl_down(s, off);
    if ((tid & 63) == 0) red[tid >> 6] = s;
    __syncthreads();
    if (tid == 0) {
        const float total = red[0] + red[1] + red[2] + red[3];
        out[DIFF_OFF] = 0.25f * (total / (float)(N_VEC * D_DIM));
        out[PERP_OFF] = 1.0f;   // exp(-log1p(1e-12)) == 1.0f in fp32
    }
}

// ---------------- launcher ----------------
extern "C" void kernel_launch(void* const* d_in, const int* in_sizes, int n_in,
                              void* d_out, int out_size, void* d_ws, size_t ws_size,
                              hipStream_t stream) {
    const float* Z = (const float*)d_in[0];   // (16,32,32,256) fp32
    const float* E = (const float*)d_in[1];   // (8192,256) fp32
    float* out = (float*)d_out;
    char*  ws  = (char*)d_ws;                 // needs ~610 KB

    float* enorm    = (float*)(ws + WS_ENORM);
    float* pbest    = (float*)(ws + WS_PBEST);
    int*   pk       = (int*)  (ws + WS_PK);
    int*   idx_i    = (int*)  (ws + WS_IDX);
    float* partials = (float*)(ws + WS_PART);

    hipLaunchKernelGGL(enorm_kernel, dim3(K_CODES / 4), dim3(256), 0, stream, E, enorm);
    hipLaunchKernelGGL(vq_argmin_kernel, dim3(N_VEC / BM, KSPLIT), dim3(256), 0, stream,
                       Z, E, enorm, pbest, pk);
    hipLaunchKernelGGL(merge_kernel, dim3(N_VEC / 256), dim3(256), 0, stream,
                       pbest, pk, idx_i, out + IDX_OFF);
    hipLaunchKernelGGL(gather_kernel, dim3(N_VEC / 64), dim3(256), 0, stream,
                       Z, E, idx_i, out, partials);
    hipLaunchKernelGGL(final_kernel, dim3(1), dim3(256), 0, stream, partials, out);
}

// Round 2
// 225.293 us; speedup vs baseline: 3.9991x; 3.9991x over previous
//
#include <hip/hip_runtime.h>
#include <hip/hip_bf16.h>

// ---------------- problem constants ----------------
#define N_VEC   16384      // 16*32*32 latent vectors
#define K_CODES 8192
#define D_DIM   256
#define NSPLIT  8          // code-dim splits (grid.y); each block: 8 k-tiles of 128
#define KT_PER  8          // K_CODES / 128 / NSPLIT
#define BM      128
#define BN      128

// d_out layout (float32 elements)
#define ZQ_SIZE  (16*256*32*32)          // 4194304
#define DIFF_OFF ZQ_SIZE
#define IDX_OFF  (ZQ_SIZE + 1)
#define PERP_OFF (ZQ_SIZE + 1 + N_VEC)

// ws layout (bytes); ~27.4 MB
#define WS_ENORM 0
#define WS_ZH    65536
#define WS_ZL    (WS_ZH + N_VEC * D_DIM * 2)      // 8454144
#define WS_EH    (WS_ZL + N_VEC * D_DIM * 2)      // 16842752
#define WS_EL    (WS_EH + K_CODES * D_DIM * 2)    // 21037056
#define WS_P2    (WS_EL + K_CODES * D_DIM * 2)    // 25231360 (ulonglong2 per (ksp,row))
#define WS_IDXI  (WS_P2 + NSPLIT * N_VEC * 16)    // 27328512
#define WS_LOSS  (WS_IDXI + N_VEC * 4)            // 27394048

typedef short bf16x8 __attribute__((ext_vector_type(8)));
typedef float f32x4  __attribute__((ext_vector_type(4)));

// RNE fp32 -> bf16 (bits in low 16)
__device__ __forceinline__ unsigned bf16r(float x) {
    unsigned u = __float_as_uint(x);
    return (u + 0x7fffu + ((u >> 16) & 1u)) >> 16;
}

// monotone (score, idx) 64-bit key: smaller key = smaller score, tie -> smaller idx
__device__ __forceinline__ unsigned long long skey(float s, int c) {
    unsigned u = __float_as_uint(s);
    u ^= (unsigned)((int)u >> 31) | 0x80000000u;
    return ((unsigned long long)u << 13) | (unsigned)c;
}

// swizzled byte offset within a 16 KB tile: logical (row 0..127, dloc 0..63 bf16)
// slot = dloc>>3 (8 x 16B slots per 128B row), swizzle slot ^= row&7  -> 2-way max on ds_read_b128
__device__ __forceinline__ int swz_off(int row, int dloc) {
    return row * 128 + ((((dloc >> 3) ^ (row & 7))) << 4) + ((dloc & 7) << 1);
}

__device__ __forceinline__ void gload16(const void* g, void* l) {
    __builtin_amdgcn_global_load_lds((const __attribute__((address_space(1))) unsigned int*)g,
                                     (__attribute__((address_space(3))) unsigned int*)l,
                                     16, 0, 0);
}

// ---------------- kernel 0: fp32 -> bf16 hi/lo, pre-tiled + swizzled ----------------
__global__ __launch_bounds__(256) void convert_kernel(const float* __restrict__ Z,
                                                      const float* __restrict__ E,
                                                      char* __restrict__ ws) {
    const int t  = threadIdx.x;
    const int r  = blockIdx.x * 4 + (t >> 6);   // 0..24575
    const int d0 = (t & 63) * 4;
    const float* src;
    char *dh, *dl;
    int rowl;
    if (r < N_VEC) {
        src  = Z + (size_t)r * D_DIM;
        rowl = r & 127;
        const int tb = (((r >> 7) * 4) + (d0 >> 6)) * 16384;
        dh = ws + WS_ZH + tb;  dl = ws + WS_ZL + tb;
    } else {
        const int re = r - N_VEC;
        src  = E + (size_t)re * D_DIM;
        rowl = re & 127;
        const int tb = (((re >> 7) * 4) + (d0 >> 6)) * 16384;
        dh = ws + WS_EH + tb;  dl = ws + WS_EL + tb;
    }
    const float4 v = *reinterpret_cast<const float4*>(src + d0);
    const unsigned h0 = bf16r(v.x), h1 = bf16r(v.y), h2 = bf16r(v.z), h3 = bf16r(v.w);
    const float f0 = __uint_as_float(h0 << 16), f1 = __uint_as_float(h1 << 16);
    const float f2 = __uint_as_float(h2 << 16), f3 = __uint_as_float(h3 << 16);
    const unsigned l0 = bf16r(v.x - f0), l1 = bf16r(v.y - f1);
    const unsigned l2 = bf16r(v.z - f2), l3 = bf16r(v.w - f3);
    uint2 hi, lo;
    hi.x = h0 | (h1 << 16);  hi.y = h2 | (h3 << 16);
    lo.x = l0 | (l1 << 16);  lo.y = l2 | (l3 << 16);
    const int off = swz_off(rowl, d0 & 63);
    *reinterpret_cast<uint2*>(dh + off) = hi;
    *reinterpret_cast<uint2*>(dl + off) = lo;
}

// ---------------- kernel 1: codebook norms ----------------
__global__ __launch_bounds__(256) void enorm_kernel(const float* __restrict__ E,
                                                    float* __restrict__ enorm) {
    const int tid  = threadIdx.x;
    const int lane = tid & 63;
    const int wid  = tid >> 6;
    const int code = blockIdx.x * 4 + wid;
    const float4 v = *reinterpret_cast<const float4*>(E + (size_t)code * D_DIM + lane * 4);
    float s = v.x * v.x + v.y * v.y + v.z * v.z + v.w * v.w;
    #pragma unroll
    for (int off = 32; off; off >>= 1) s += __shfl_down(s, off);
    if (lane == 0) enorm[code] = s;
}

// ---------------- kernel 2: split-bf16 MFMA distance GEMM + per-row top-2 screen ----------------
__global__ __launch_bounds__(256, 2) void vq_mfma_kernel(const char* __restrict__ ws_ro,
                                                         ulonglong2* __restrict__ part2) {
    __shared__ short lds[4 * 8192];   // 4 tiles x 16 KB = 64 KB (Ah, Al, Bh, Bl)

    const int tid  = threadIdx.x;
    const int lane = tid & 63, wid = tid >> 6;
    const int lane15 = lane & 15, g = lane >> 4;
    const int wm = wid >> 1, wn = wid & 1;
    const int bx = blockIdx.x, ksp = blockIdx.y;
    const int row0 = bx * BM;

    const char* zh = ws_ro + WS_ZH;
    const char* zl = ws_ro + WS_ZL;
    const char* eh = ws_ro + WS_EH;
    const char* el = ws_ro + WS_EL;
    const float* enorm = (const float*)(ws_ro + WS_ENORM);

    unsigned long long slots[16];
    #pragma unroll
    for (int i = 0; i < 16; ++i) slots[i] = ~0ull;

    for (int kt = 0; kt < KT_PER; ++kt) {
        const int kofs  = ksp * (K_CODES / NSPLIT) + kt * BN;
        const int ktile = kofs >> 7;

        float en[4];
        #pragma unroll
        for (int n = 0; n < 4; ++n) en[n] = enorm[kofs + wn * 64 + n * 16 + lane15];

        f32x4 acc[4][4];
        #pragma unroll
        for (int m = 0; m < 4; ++m)
            #pragma unroll
            for (int n = 0; n < 4; ++n)
                #pragma unroll
                for (int q = 0; q < 4; ++q) acc[m][n][q] = 0.0f;

        for (int dt = 0; dt < 4; ++dt) {
            __syncthreads();
            // stage 4 tiles (16 KB each) via global_load_lds width-16; layout identity
            const size_t tA = (size_t)(bx * 4 + dt) * 16384 + wid * 4096 + lane * 16;
            const size_t tB = (size_t)(ktile * 4 + dt) * 16384 + wid * 4096 + lane * 16;
            short* lA = lds + wid * 2048;             // shorts: 4096 B = 2048 shorts
            #pragma unroll
            for (int i = 0; i < 4; ++i) {
                gload16(zh + tA + i * 1024, lA + 0 * 8192 + i * 512);
                gload16(zl + tA + i * 1024, lA + 1 * 8192 + i * 512);
                gload16(eh + tB + i * 1024, lA + 2 * 8192 + i * 512);
                gload16(el + tB + i * 1024, lA + 3 * 8192 + i * 512);
            }
            __syncthreads();

            #pragma unroll
            for (int ksub = 0; ksub < 2; ++ksub) {
                bf16x8 aH[4], aL[4], bH[4], bL[4];
                #pragma unroll
                for (int m = 0; m < 4; ++m) {
                    const int row = wm * 64 + m * 16 + lane15;
                    const int off = (row * 128 + ((((ksub * 4 + g)) ^ (row & 7)) << 4)) >> 1;
                    aH[m] = *reinterpret_cast<const bf16x8*>(lds + 0 * 8192 + off);
                    aL[m] = *reinterpret_cast<const bf16x8*>(lds + 1 * 8192 + off);
                }
                #pragma unroll
                for (int n = 0; n < 4; ++n) {
                    const int col = wn * 64 + n * 16 + lane15;
                    const int off = (col * 128 + ((((ksub * 4 + g)) ^ (col & 7)) << 4)) >> 1;
                    bH[n] = *reinterpret_cast<const bf16x8*>(lds + 2 * 8192 + off);
                    bL[n] = *reinterpret_cast<const bf16x8*>(lds + 3 * 8192 + off);
                }
                #pragma unroll
                for (int m = 0; m < 4; ++m)
                    #pragma unroll
                    for (int n = 0; n < 4; ++n) {
                        acc[m][n] = __builtin_amdgcn_mfma_f32_16x16x32_bf16(aH[m], bH[n], acc[m][n], 0, 0, 0);
                        acc[m][n] = __builtin_amdgcn_mfma_f32_16x16x32_bf16(aH[m], bL[n], acc[m][n], 0, 0, 0);
                        acc[m][n] = __builtin_amdgcn_mfma_f32_16x16x32_bf16(aL[m], bH[n], acc[m][n], 0, 0, 0);
                    }
            }
        }

        // epilogue: score = ||e||^2 - 2 z.e ; fold into per-lane per-row top-1 keys
        #pragma unroll
        for (int m = 0; m < 4; ++m)
            #pragma unroll
            for (int n = 0; n < 4; ++n) {
                const int c = kofs + wn * 64 + n * 16 + lane15;
                #pragma unroll
                for (int q = 0; q < 4; ++q) {
                    const float s = fmaf(-2.0f, acc[m][n][q], en[n]);
                    const unsigned long long k = skey(s, c);
                    const int sl = m * 4 + q;
                    slots[sl] = (k < slots[sl]) ? k : slots[sl];
                }
            }
    }

    // block-level top-2 per row: butterfly across the 16 lanes sharing each row
    __syncthreads();
    unsigned long long* t2 = reinterpret_cast<unsigned long long*>(lds);  // [wid][64][2]
    #pragma unroll
    for (int sl = 0; sl < 16; ++sl) {
        const int m = sl >> 2, q = sl & 3;
        const unsigned long long k1 = slots[sl];
        unsigned long long m1 = k1;
        #pragma unroll
        for (int msk = 1; msk < 16; msk <<= 1) {
            const unsigned long long o = __shfl_xor(m1, msk);
            m1 = (o < m1) ? o : m1;
        }
        unsigned long long k2 = (k1 == m1) ? ~0ull : k1;
        #pragma unroll
        for (int msk = 1; msk < 16; msk <<= 1) {
            const unsigned long long o = __shfl_xor(k2, msk);
            k2 = (o < k2) ? o : k2;
        }
        if (lane15 == 0) {
            const int row64 = m * 16 + g * 4 + q;
            t2[(wid * 64 + row64) * 2 + 0] = m1;
            t2[(wid * 64 + row64) * 2 + 1] = k2;
        }
    }
    __syncthreads();
    if (tid < 128) {
        const int wm2 = tid >> 6, r64 = tid & 63;
        const unsigned long long a1 = t2[((wm2 * 2 + 0) * 64 + r64) * 2 + 0];
        const unsigned long long a2 = t2[((wm2 * 2 + 0) * 64 + r64) * 2 + 1];
        const unsigned long long b1 = t2[((wm2 * 2 + 1) * 64 + r64) * 2 + 0];
        const unsigned long long b2 = t2[((wm2 * 2 + 1) * 64 + r64) * 2 + 1];
        const unsigned long long r1 = (a1 < b1) ? a1 : b1;
        const unsigned long long hi = (a1 < b1) ? b1 : a1;
        const unsigned long long l2 = (a2 < b2) ? a2 : b2;
        const unsigned long long r2 = (hi < l2) ? hi : l2;
        ulonglong2 res;  res.x = r1;  res.y = r2;
        part2[(size_t)ksp * N_VEC + row0 + tid] = res;
    }
}

// ---------------- kernel 3: merge splits + exact fp64 rescore of top-2 ----------------
__global__ __launch_bounds__(256) void rescore_kernel(const float* __restrict__ Z,
                                                      const float* __restrict__ E,
                                                      const ulonglong2* __restrict__ part2,
                                                      int* __restrict__ idx_i,
                                                      float* __restrict__ out_idx) {
    const int tid = threadIdx.x, lane = tid & 63, wid = tid >> 6;
    const int r = blockIdx.x * 4 + wid;
    int c1 = 0, c2 = 0;
    if (lane == 0) {
        unsigned long long m1 = ~0ull, m2 = ~0ull;
        for (int s = 0; s < NSPLIT; ++s) {
            const ulonglong2 p = part2[(size_t)s * N_VEC + r];
            if (p.x < m1) { m2 = m1; m1 = p.x; } else if (p.x < m2) { m2 = p.x; }
            if (p.y < m1) { m2 = m1; m1 = p.y; } else if (p.y < m2) { m2 = p.y; }
        }
        c1 = (int)(m1 & 0x1FFFull);
        c2 = (int)(m2 & 0x1FFFull);
    }
    c1 = __shfl(c1, 0);
    c2 = __shfl(c2, 0);
    const float4 z4 = *reinterpret_cast<const float4*>(Z + (size_t)r  * D_DIM + lane * 4);
    const float4 e1 = *reinterpret_cast<const float4*>(E + (size_t)c1 * D_DIM + lane * 4);
    const float4 e2 = *reinterpret_cast<const float4*>(E + (size_t)c2 * D_DIM + lane * 4);
    double d1, d2;
    {
        const double ax = (double)z4.x - (double)e1.x, ay = (double)z4.y - (double)e1.y;
        const double az = (double)z4.z - (double)e1.z, aw = (double)z4.w - (double)e1.w;
        d1 = ax * ax + ay * ay + az * az + aw * aw;
        const double bx = (double)z4.x - (double)e2.x, by = (double)z4.y - (double)e2.y;
        const double bz = (double)z4.z - (double)e2.z, bw = (double)z4.w - (double)e2.w;
        d2 = bx * bx + by * by + bz * bz + bw * bw;
    }
    #pragma unroll
    for (int off = 1; off < 64; off <<= 1) {
        d1 += __shfl_xor(d1, off);
        d2 += __shfl_xor(d2, off);
    }
    if (lane == 0) {
        const int idx = (d2 < d1) ? c2 : ((d1 < d2) ? c1 : (c1 < c2 ? c1 : c2));
        idx_i[r]   = idx;
        out_idx[r] = (float)idx;
    }
}

// ---------------- kernel 4: gather + NCHW transpose + commitment-loss partial ----------------
__global__ __launch_bounds__(256) void gather_kernel(const float* __restrict__ Z,
                                                     const float* __restrict__ E,
                                                     const int* __restrict__ idx_i,
                                                     float* __restrict__ out,
                                                     float* __restrict__ partials) {
    __shared__ float Ls[128 * 65];
    __shared__ int   sIdx[64];
    __shared__ float red[4];

    const int tid = threadIdx.x;
    const int gb  = blockIdx.x;       // 0..255, 64 latent vectors each
    const int n0  = gb * 64;
    const int b   = n0 >> 10;
    const int hwbase = n0 & 1023;

    if (tid < 64) sIdx[tid] = idx_i[n0 + tid];
    __syncthreads();

    float sq = 0.0f;
    {
        const int c4   = tid & 63;
        const int rsub = tid >> 6;
        #pragma unroll
        for (int p = 0; p < 16; ++p) {
            const int r = p * 4 + rsub;
            const float4 z4 = *reinterpret_cast<const float4*>(Z + (size_t)(n0 + r) * D_DIM + c4 * 4);
            const float4 e4 = *reinterpret_cast<const float4*>(E + (size_t)sIdx[r] * D_DIM + c4 * 4);
            const float dx = e4.x - z4.x, dy = e4.y - z4.y, dz = e4.z - z4.z, dw = e4.w - z4.w;
            sq += dx * dx + dy * dy + dz * dz + dw * dw;
        }
    }
    #pragma unroll
    for (int off = 32; off; off >>= 1) sq += __shfl_down(sq, off);
    if ((tid & 63) == 0) red[tid >> 6] = sq;
    __syncthreads();
    if (tid == 0) partials[gb] = red[0] + red[1] + red[2] + red[3];

    for (int h = 0; h < 2; ++h) {
        __syncthreads();
        const int rowl = tid >> 2;
        const int qs   = tid & 3;
        const float* erow = E + (size_t)sIdx[rowl] * D_DIM + h * 128;
        #pragma unroll
        for (int m = 0; m < 8; ++m) {
            const int c4 = m * 4 + qs;
            const float4 v = *reinterpret_cast<const float4*>(erow + c4 * 4);
            Ls[(c4 * 4 + 0) * 65 + rowl] = v.x;
            Ls[(c4 * 4 + 1) * 65 + rowl] = v.y;
            Ls[(c4 * 4 + 2) * 65 + rowl] = v.z;
            Ls[(c4 * 4 + 3) * 65 + rowl] = v.w;
        }
        __syncthreads();
        const int wl   = tid & 63;
        const int csub = tid >> 6;
        #pragma unroll
        for (int pc = 0; pc < 32; ++pc) {
            const int c_l = pc * 4 + csub;
            const int c   = h * 128 + c_l;
            out[((size_t)(b * 256 + c)) * 1024 + hwbase + wl] = Ls[c_l * 65 + wl];
        }
    }
}

// ---------------- kernel 5: finalize scalars ----------------
__global__ __launch_bounds__(256) void final_kernel(const float* __restrict__ partials,
                                                    float* __restrict__ out) {
    __shared__ float red[4];
    const int tid = threadIdx.x;
    float s = partials[tid];
    #pragma unroll
    for (int off = 32; off; off >>= 1) s += __shfl_down(s, off);
    if ((tid & 63) == 0) red[tid >> 6] = s;
    __syncthreads();
    if (tid == 0) {
        const float total = red[0] + red[1] + red[2] + red[3];
        out[DIFF_OFF] = 0.25f * (total / (float)(N_VEC * D_DIM));
        out[PERP_OFF] = 1.0f;
    }
}

// ---------------- launcher ----------------
extern "C" void kernel_launch(void* const* d_in, const int* in_sizes, int n_in,
                              void* d_out, int out_size, void* d_ws, size_t ws_size,
                              hipStream_t stream) {
    const float* Z = (const float*)d_in[0];   // (16,32,32,256) fp32
    const float* E = (const float*)d_in[1];   // (8192,256) fp32
    float* out = (float*)d_out;
    char*  ws  = (char*)d_ws;                 // needs ~27.4 MB

    float*      enorm    = (float*)(ws + WS_ENORM);
    ulonglong2* part2    = (ulonglong2*)(ws + WS_P2);
    int*        idx_i    = (int*)(ws + WS_IDXI);
    float*      lossbuf  = (float*)(ws + WS_LOSS);

    hipLaunchKernelGGL(convert_kernel, dim3((N_VEC + K_CODES) / 4), dim3(256), 0, stream, Z, E, ws);
    hipLaunchKernelGGL(enorm_kernel, dim3(K_CODES / 4), dim3(256), 0, stream, E, enorm);
    hipLaunchKernelGGL(vq_mfma_kernel, dim3(N_VEC / BM, NSPLIT), dim3(256), 0, stream,
                       (const char*)ws, part2);
    hipLaunchKernelGGL(rescore_kernel, dim3(N_VEC / 4), dim3(256), 0, stream,
                       Z, E, part2, idx_i, out + IDX_OFF);
    hipLaunchKernelGGL(gather_kernel, dim3(N_VEC / 64), dim3(256), 0, stream,
                       Z, E, idx_i, out, lossbuf);
    hipLaunchKernelGGL(final_kernel, dim3(1), dim3(256), 0, stream, lossbuf, out);
}

// Round 3
// 128.119 us; speedup vs baseline: 7.0323x; 1.7585x over previous
//
#include <hip/hip_runtime.h>
#include <hip/hip_bf16.h>
#include <hip/hip_fp16.h>

// ---------------- problem constants ----------------
#define N_VEC   16384      // 16*32*32 latent vectors
#define K_CODES 8192
#define D_DIM   256
#define NSPLIT  8          // code-dim splits (grid.y); each block: 8 k-tiles of 128
#define BM      128
#define BN      128

// d_out layout (float32 elements)
#define ZQ_SIZE  (16*256*32*32)          // 4194304
#define DIFF_OFF ZQ_SIZE
#define IDX_OFF  (ZQ_SIZE + 1)
#define PERP_OFF (ZQ_SIZE + 1 + N_VEC)

// ws layout (bytes); ~14.7 MB
#define WS_ENORM 0
#define WS_ZH    65536
#define WS_EH    (WS_ZH + N_VEC * D_DIM * 2)      // +8 MB
#define WS_P2    (WS_EH + K_CODES * D_DIM * 2)    // +4 MB
#define WS_IDXI  (WS_P2 + NSPLIT * N_VEC * 16)    // +2 MB
#define WS_LOSS  (WS_IDXI + N_VEC * 4)

typedef _Float16 f16x8 __attribute__((ext_vector_type(8)));
typedef float    f32x4 __attribute__((ext_vector_type(4)));

// monotone (score, idx) 64-bit key: smaller key = smaller score, tie -> smaller idx
__device__ __forceinline__ unsigned long long skey(float s, int c) {
    unsigned u = __float_as_uint(s);
    u ^= (unsigned)((int)u >> 31) | 0x80000000u;
    return ((unsigned long long)u << 13) | (unsigned)c;
}

// swizzled byte offset within a 16 KB tile: logical (row 0..127, dloc 0..63 f16)
// slot = dloc>>3 (8 x 16B slots per 128B row), slot ^= row&7 -> conflict-free ds_read_b128
__device__ __forceinline__ int swz_off(int row, int dloc) {
    return row * 128 + ((((dloc >> 3) ^ (row & 7))) << 4) + ((dloc & 7) << 1);
}

__device__ __forceinline__ void gload16(const void* g, void* l) {
    __builtin_amdgcn_global_load_lds((const __attribute__((address_space(1))) unsigned int*)g,
                                     (__attribute__((address_space(3))) unsigned int*)l,
                                     16, 0, 0);
}

// ---------------- kernel 0: fp32 -> fp16, pre-tiled + swizzled ----------------
__global__ __launch_bounds__(256) void convert_kernel(const float* __restrict__ Z,
                                                      const float* __restrict__ E,
                                                      char* __restrict__ ws) {
    const int t  = threadIdx.x;
    const int r  = blockIdx.x * 4 + (t >> 6);   // 0..24575
    const int d0 = (t & 63) * 4;
    const float* src;
    char* dh;
    int rowl;
    if (r < N_VEC) {
        src  = Z + (size_t)r * D_DIM;
        rowl = r & 127;
        dh = ws + WS_ZH + (size_t)(((r >> 7) * 4) + (d0 >> 6)) * 16384;
    } else {
        const int re = r - N_VEC;
        src  = E + (size_t)re * D_DIM;
        rowl = re & 127;
        dh = ws + WS_EH + (size_t)(((re >> 7) * 4) + (d0 >> 6)) * 16384;
    }
    const float4 v = *reinterpret_cast<const float4*>(src + d0);
    const unsigned h0 = __half_as_ushort(__float2half(v.x));
    const unsigned h1 = __half_as_ushort(__float2half(v.y));
    const unsigned h2 = __half_as_ushort(__float2half(v.z));
    const unsigned h3 = __half_as_ushort(__float2half(v.w));
    uint2 hi;
    hi.x = h0 | (h1 << 16);  hi.y = h2 | (h3 << 16);
    *reinterpret_cast<uint2*>(dh + swz_off(rowl, d0 & 63)) = hi;
}

// ---------------- kernel 1: codebook norms (fp32 exact) ----------------
__global__ __launch_bounds__(256) void enorm_kernel(const float* __restrict__ E,
                                                    float* __restrict__ enorm) {
    const int tid  = threadIdx.x;
    const int lane = tid & 63;
    const int wid  = tid >> 6;
    const int code = blockIdx.x * 4 + wid;
    const float4 v = *reinterpret_cast<const float4*>(E + (size_t)code * D_DIM + lane * 4);
    float s = v.x * v.x + v.y * v.y + v.z * v.z + v.w * v.w;
    #pragma unroll
    for (int off = 32; off; off >>= 1) s += __shfl_down(s, off);
    if (lane == 0) enorm[code] = s;
}

// ---------------- kernel 2: fp16 MFMA distance screen + per-split top-2 ----------------
__global__ __launch_bounds__(256, 2) void vq_mfma_kernel(const char* __restrict__ ws_ro,
                                                         ulonglong2* __restrict__ part2) {
    __shared__ short lds[32768];   // 2 bufs x (A 16KB + B 16KB) = 64 KB

    const int tid  = threadIdx.x;
    const int lane = tid & 63, wid = tid >> 6;
    const int lane15 = lane & 15, g = lane >> 4;
    const int wm = wid >> 1, wn = wid & 1;
    const int bx = blockIdx.x, ksp = blockIdx.y;
    const int row0 = bx * BM;

    const char* zh = ws_ro + WS_ZH;
    const char* eh = ws_ro + WS_EH;
    const float* enorm = (const float*)(ws_ro + WS_ENORM);

    // precomputed fragment read offsets (short index), ksub=0; ksub=1 -> ^32
    int aoff[4], boff[4];
    #pragma unroll
    for (int m = 0; m < 4; ++m) {
        const int row = wm * 64 + m * 16 + lane15;
        aoff[m] = (row * 128 + ((g ^ (row & 7)) << 4)) >> 1;
    }
    #pragma unroll
    for (int n = 0; n < 4; ++n) {
        const int col = wn * 64 + n * 16 + lane15;
        boff[n] = ((col * 128 + ((g ^ (col & 7)) << 4)) >> 1) + 8192;
    }

    // per-lane per-slot running min (float,int) — cheap fold, keys built only in tail
    float bestv[16];
    int   bestc[16];
    #pragma unroll
    for (int i = 0; i < 16; ++i) { bestv[i] = 3.0e38f; bestc[i] = 0; }

    // staging: step s = kt*4+dt; per wave 8 x gload16 (4 A + 4 B)
    #define STAGE(s_)                                                              \
    do {                                                                           \
        const int s__ = (s_);                                                      \
        const int kt_ = s__ >> 2, dt_ = s__ & 3;                                   \
        const char* sA = zh + (size_t)(bx * 4 + dt_) * 16384 + wid * 4096 + lane * 16; \
        const char* sB = eh + (size_t)((ksp * 8 + kt_) * 4 + dt_) * 16384 + wid * 4096 + lane * 16; \
        short* dA = lds + (s__ & 1) * 16384 + wid * 2048 + lane * 8;               \
        short* dB = dA + 8192;                                                     \
        _Pragma("unroll")                                                          \
        for (int i_ = 0; i_ < 4; ++i_) {                                           \
            gload16(sA + i_ * 1024, dA + i_ * 512);                                \
            gload16(sB + i_ * 1024, dB + i_ * 512);                                \
        }                                                                          \
    } while (0)

    STAGE(0);
    __syncthreads();

    for (int kt = 0; kt < 8; ++kt) {
        const int kofs = ksp * (K_CODES / NSPLIT) + kt * BN;

        float en[4];
        #pragma unroll
        for (int n = 0; n < 4; ++n) en[n] = enorm[kofs + wn * 64 + n * 16 + lane15];

        f32x4 acc[4][4];
        #pragma unroll
        for (int m = 0; m < 4; ++m)
            #pragma unroll
            for (int n = 0; n < 4; ++n)
                #pragma unroll
                for (int q = 0; q < 4; ++q) acc[m][n][q] = 0.0f;

        for (int dt = 0; dt < 4; ++dt) {
            const int s = kt * 4 + dt;
            if (s + 1 < 32) STAGE(s + 1);          // prefetch next step into other buffer
            const int cb = (s & 1) * 16384;

            #pragma unroll
            for (int ksub = 0; ksub < 2; ++ksub) {
                f16x8 a[4], b[4];
                const int x = ksub << 5;           // byte ^0x40 -> short-index ^32
                #pragma unroll
                for (int m = 0; m < 4; ++m)
                    a[m] = *reinterpret_cast<const f16x8*>(lds + cb + (aoff[m] ^ x));
                #pragma unroll
                for (int n = 0; n < 4; ++n)
                    b[n] = *reinterpret_cast<const f16x8*>(lds + cb + (boff[n] ^ x));
                #pragma unroll
                for (int m = 0; m < 4; ++m)
                    #pragma unroll
                    for (int n = 0; n < 4; ++n)
                        acc[m][n] = __builtin_amdgcn_mfma_f32_16x16x32_f16(a[m], b[n], acc[m][n], 0, 0, 0);
            }
            __syncthreads();                       // drains prefetch loads + flips buffer
        }

        // epilogue fold: score = ||e||^2 - 2 z.e ; scan order (kt, n) ascending -> first-min
        #pragma unroll
        for (int m = 0; m < 4; ++m)
            #pragma unroll
            for (int n = 0; n < 4; ++n) {
                const int c = kofs + wn * 64 + n * 16 + lane15;
                #pragma unroll
                for (int q = 0; q < 4; ++q) {
                    const float sc = fmaf(-2.0f, acc[m][n][q], en[n]);
                    const int sl = m * 4 + q;
                    if (sc < bestv[sl]) { bestv[sl] = sc; bestc[sl] = c; }
                }
            }
    }
    #undef STAGE

    // tail: per-row top-2 over the 16 lanes sharing each row (lexicographic keys)
    unsigned long long* t2 = reinterpret_cast<unsigned long long*>(lds);  // [wid][64][2]
    #pragma unroll
    for (int sl = 0; sl < 16; ++sl) {
        const int m = sl >> 2, q = sl & 3;
        const unsigned long long k1 = skey(bestv[sl], bestc[sl]);
        unsigned long long m1 = k1;
        #pragma unroll
        for (int msk = 1; msk < 16; msk <<= 1) {
            const unsigned long long o = __shfl_xor(m1, msk);
            m1 = (o < m1) ? o : m1;
        }
        unsigned long long k2 = (k1 == m1) ? ~0ull : k1;
        #pragma unroll
        for (int msk = 1; msk < 16; msk <<= 1) {
            const unsigned long long o = __shfl_xor(k2, msk);
            k2 = (o < k2) ? o : k2;
        }
        if (lane15 == 0) {
            const int row64 = m * 16 + g * 4 + q;
            t2[(wid * 64 + row64) * 2 + 0] = m1;
            t2[(wid * 64 + row64) * 2 + 1] = k2;
        }
    }
    __syncthreads();
    if (tid < 128) {
        const int wm2 = tid >> 6, r64 = tid & 63;
        const unsigned long long a1 = t2[((wm2 * 2 + 0) * 64 + r64) * 2 + 0];
        const unsigned long long a2 = t2[((wm2 * 2 + 0) * 64 + r64) * 2 + 1];
        const unsigned long long b1 = t2[((wm2 * 2 + 1) * 64 + r64) * 2 + 0];
        const unsigned long long b2 = t2[((wm2 * 2 + 1) * 64 + r64) * 2 + 1];
        const unsigned long long r1 = (a1 < b1) ? a1 : b1;
        const unsigned long long hi = (a1 < b1) ? b1 : a1;
        const unsigned long long l2 = (a2 < b2) ? a2 : b2;
        const unsigned long long r2 = (hi < l2) ? hi : l2;
        ulonglong2 res;  res.x = r1;  res.y = r2;
        part2[(size_t)ksp * N_VEC + row0 + tid] = res;
    }
}

// ---------------- kernel 3: merge splits + exact fp64 rescore of global top-4 ----------------
__global__ __launch_bounds__(256) void rescore_kernel(const float* __restrict__ Z,
                                                      const float* __restrict__ E,
                                                      const ulonglong2* __restrict__ part2,
                                                      int* __restrict__ idx_i,
                                                      float* __restrict__ out_idx) {
    const int tid = threadIdx.x, lane = tid & 63, wid = tid >> 6;
    const int r = blockIdx.x * 4 + wid;
    int c0 = 0, c1 = 0, c2 = 0, c3 = 0;
    if (lane == 0) {
        unsigned long long m0 = ~0ull, m1 = ~0ull, m2 = ~0ull, m3 = ~0ull;
        for (int s = 0; s < NSPLIT; ++s) {
            const ulonglong2 p = part2[(size_t)s * N_VEC + r];
            unsigned long long k = p.x;
            if (k < m0) { m3 = m2; m2 = m1; m1 = m0; m0 = k; }
            else if (k < m1) { m3 = m2; m2 = m1; m1 = k; }
            else if (k < m2) { m3 = m2; m2 = k; }
            else if (k < m3) { m3 = k; }
            k = p.y;
            if (k < m0) { m3 = m2; m2 = m1; m1 = m0; m0 = k; }
            else if (k < m1) { m3 = m2; m2 = m1; m1 = k; }
            else if (k < m2) { m3 = m2; m2 = k; }
            else if (k < m3) { m3 = k; }
        }
        c0 = (int)(m0 & 0x1FFFull);  c1 = (int)(m1 & 0x1FFFull);
        c2 = (int)(m2 & 0x1FFFull);  c3 = (int)(m3 & 0x1FFFull);
    }
    c0 = __shfl(c0, 0);  c1 = __shfl(c1, 0);
    c2 = __shfl(c2, 0);  c3 = __shfl(c3, 0);
    const float4 z4 = *reinterpret_cast<const float4*>(Z + (size_t)r * D_DIM + lane * 4);
    double d[4];
    const int cc[4] = {c0, c1, c2, c3};
    #pragma unroll
    for (int j = 0; j < 4; ++j) {
        const float4 e4 = *reinterpret_cast<const float4*>(E + (size_t)cc[j] * D_DIM + lane * 4);
        const double ax = (double)z4.x - (double)e4.x, ay = (double)z4.y - (double)e4.y;
        const double az = (double)z4.z - (double)e4.z, aw = (double)z4.w - (double)e4.w;
        d[j] = ax * ax + ay * ay + az * az + aw * aw;
    }
    #pragma unroll
    for (int off = 1; off < 64; off <<= 1) {
        #pragma unroll
        for (int j = 0; j < 4; ++j) d[j] += __shfl_xor(d[j], off);
    }
    if (lane == 0) {
        double bd = d[0];  int bi = c0;
        #pragma unroll
        for (int j = 1; j < 4; ++j) {
            if (d[j] < bd || (d[j] == bd && cc[j] < bi)) { bd = d[j]; bi = cc[j]; }
        }
        idx_i[r]   = bi;
        out_idx[r] = (float)bi;
    }
}

// ---------------- kernel 4: gather + NCHW transpose + commitment-loss partial ----------------
__global__ __launch_bounds__(256) void gather_kernel(const float* __restrict__ Z,
                                                     const float* __restrict__ E,
                                                     const int* __restrict__ idx_i,
                                                     float* __restrict__ out,
                                                     float* __restrict__ partials) {
    __shared__ float Ls[128 * 65];
    __shared__ int   sIdx[64];
    __shared__ float red[4];

    const int tid = threadIdx.x;
    const int gb  = blockIdx.x;       // 0..255, 64 latent vectors each
    const int n0  = gb * 64;
    const int b   = n0 >> 10;
    const int hwbase = n0 & 1023;

    if (tid < 64) sIdx[tid] = idx_i[n0 + tid];
    __syncthreads();

    float sq = 0.0f;
    {
        const int c4   = tid & 63;
        const int rsub = tid >> 6;
        #pragma unroll
        for (int p = 0; p < 16; ++p) {
            const int r = p * 4 + rsub;
            const float4 z4 = *reinterpret_cast<const float4*>(Z + (size_t)(n0 + r) * D_DIM + c4 * 4);
            const float4 e4 = *reinterpret_cast<const float4*>(E + (size_t)sIdx[r] * D_DIM + c4 * 4);
            const float dx = e4.x - z4.x, dy = e4.y - z4.y, dz = e4.z - z4.z, dw = e4.w - z4.w;
            sq += dx * dx + dy * dy + dz * dz + dw * dw;
        }
    }
    #pragma unroll
    for (int off = 32; off; off >>= 1) sq += __shfl_down(sq, off);
    if ((tid & 63) == 0) red[tid >> 6] = sq;
    __syncthreads();
    if (tid == 0) partials[gb] = red[0] + red[1] + red[2] + red[3];

    for (int h = 0; h < 2; ++h) {
        __syncthreads();
        const int rowl = tid >> 2;
        const int qs   = tid & 3;
        const float* erow = E + (size_t)sIdx[rowl] * D_DIM + h * 128;
        #pragma unroll
        for (int m = 0; m < 8; ++m) {
            const int c4 = m * 4 + qs;
            const float4 v = *reinterpret_cast<const float4*>(erow + c4 * 4);
            Ls[(c4 * 4 + 0) * 65 + rowl] = v.x;
            Ls[(c4 * 4 + 1) * 65 + rowl] = v.y;
            Ls[(c4 * 4 + 2) * 65 + rowl] = v.z;
            Ls[(c4 * 4 + 3) * 65 + rowl] = v.w;
        }
        __syncthreads();
        const int wl   = tid & 63;
        const int csub = tid >> 6;
        #pragma unroll
        for (int pc = 0; pc < 32; ++pc) {
            const int c_l = pc * 4 + csub;
            const int c   = h * 128 + c_l;
            out[((size_t)(b * 256 + c)) * 1024 + hwbase + wl] = Ls[c_l * 65 + wl];
        }
    }
}

// ---------------- kernel 5: finalize scalars ----------------
__global__ __launch_bounds__(256) void final_kernel(const float* __restrict__ partials,
                                                    float* __restrict__ out) {
    __shared__ float red[4];
    const int tid = threadIdx.x;
    float s = partials[tid];
    #pragma unroll
    for (int off = 32; off; off >>= 1) s += __shfl_down(s, off);
    if ((tid & 63) == 0) red[tid >> 6] = s;
    __syncthreads();
    if (tid == 0) {
        const float total = red[0] + red[1] + red[2] + red[3];
        out[DIFF_OFF] = 0.25f * (total / (float)(N_VEC * D_DIM));
        out[PERP_OFF] = 1.0f;
    }
}

// ---------------- launcher ----------------
extern "C" void kernel_launch(void* const* d_in, const int* in_sizes, int n_in,
                              void* d_out, int out_size, void* d_ws, size_t ws_size,
                              hipStream_t stream) {
    const float* Z = (const float*)d_in[0];   // (16,32,32,256) fp32
    const float* E = (const float*)d_in[1];   // (8192,256) fp32
    float* out = (float*)d_out;
    char*  ws  = (char*)d_ws;                 // needs ~14.7 MB

    float*      enorm    = (float*)(ws + WS_ENORM);
    ulonglong2* part2    = (ulonglong2*)(ws + WS_P2);
    int*        idx_i    = (int*)(ws + WS_IDXI);
    float*      lossbuf  = (float*)(ws + WS_LOSS);

    hipLaunchKernelGGL(convert_kernel, dim3((N_VEC + K_CODES) / 4), dim3(256), 0, stream, Z, E, ws);
    hipLaunchKernelGGL(enorm_kernel, dim3(K_CODES / 4), dim3(256), 0, stream, E, enorm);
    hipLaunchKernelGGL(vq_mfma_kernel, dim3(N_VEC / BM, NSPLIT), dim3(256), 0, stream,
                       (const char*)ws, part2);
    hipLaunchKernelGGL(rescore_kernel, dim3(N_VEC / 4), dim3(256), 0, stream,
                       Z, E, part2, idx_i, out + IDX_OFF);
    hipLaunchKernelGGL(gather_kernel, dim3(N_VEC / 64), dim3(256), 0, stream,
                       Z, E, idx_i, out, lossbuf);
    hipLaunchKernelGGL(final_kernel, dim3(1), dim3(256), 0, stream, lossbuf, out);
}